// Round 1
// baseline (215.893 us; speedup 1.0000x reference)
//
#include <hip/hip_runtime.h>

#define DD 128

__global__ __launch_bounds__(256) void byteshift_kernel(const float* __restrict__ x,
                                                        float* __restrict__ out,
                                                        int n_rows) {
    int tid = blockIdx.x * blockDim.x + threadIdx.x;
    int lane_r = tid & 31;      // lane within the 32-lane row group
    int row = tid >> 5;
    if (row >= n_rows) return;

    const float4* xrow = (const float4*)(x + (size_t)row * DD);
    float4 v = xrow[lane_r];    // elements d = 4*lane_r .. 4*lane_r+3

    // local argmax over this lane's 4 elements (global d index, first-occurrence)
    int dbase = lane_r * 4;
    float m = v.x; int mi = dbase;
    if (v.y > m) { m = v.y; mi = dbase + 1; }
    if (v.z > m) { m = v.z; mi = dbase + 2; }
    if (v.w > m) { m = v.w; mi = dbase + 3; }

    // butterfly argmax across each aligned group of 4 lanes (covers one 16-elem slice)
    #pragma unroll
    for (int dlt = 1; dlt <= 2; dlt <<= 1) {
        float om = __shfl_xor(m, dlt);
        int   oi = __shfl_xor(mi, dlt);
        if (om > m || (om == m && oi < mi)) { m = om; mi = oi; }
    }

    // flags live in lane 0 of each row group (d0=MARK >=0.5, d1=SHL >0.5, d2=SHR >0.5)
    int flags = (v.x >= 0.5f ? 1 : 0) | (v.y > 0.5f ? 2 : 0) | (v.z > 0.5f ? 4 : 0);
    flags = __shfl(flags, 0, 32);

    // slice argmaxes: lanes 4-7 hold d in [16,32) (ALU_LO), 8-11 -> [32,48) (ALU_HI),
    // 12-15 -> [48,64) (AX_CARRY). Slices are 16-aligned so (d & 15) is the slice index.
    int d_lo = __shfl(mi, 4, 32);
    int d_hi = __shfl(mi, 8, 32);
    int d_sh = __shfl(mi, 12, 32);

    int value = (d_lo & 15) | ((d_hi & 15) << 4);   // 0..255
    int shift = d_sh & 15;                           // <=15, min(.,31) is a no-op
    bool shl    = (flags & 2) != 0;
    bool active = (flags & 1) && (flags & 6);
    int result = shl ? ((value << shift) & 255) : (value >> shift);
    int t0 = 64 + (result & 15);
    int t1 = 80 + ((result >> 4) & 15);

    float add = active ? 2.0f : 0.0f;
    float4 o = v;
    if (dbase     == t0 || dbase     == t1) o.x += add;
    if (dbase + 1 == t0 || dbase + 1 == t1) o.y += add;
    if (dbase + 2 == t0 || dbase + 2 == t1) o.z += add;
    if (dbase + 3 == t0 || dbase + 3 == t1) o.w += add;
    ((float4*)(out + (size_t)row * DD))[lane_r] = o;
}

extern "C" void kernel_launch(void* const* d_in, const int* in_sizes, int n_in,
                              void* d_out, int out_size, void* d_ws, size_t ws_size,
                              hipStream_t stream) {
    const float* x = (const float*)d_in[0];
    float* out = (float*)d_out;
    int n_rows = in_sizes[0] / DD;          // B*S = 262144
    int threads = 256;                       // 8 rows per block
    int total = n_rows * 32;
    int blocks = (total + threads - 1) / threads;
    hipLaunchKernelGGL(byteshift_kernel, dim3(blocks), dim3(threads), 0, stream,
                       x, out, n_rows);
}